// Round 11
// baseline (1964.273 us; speedup 1.0000x reference)
//
#include <hip/hip_runtime.h>

// ---------------------------------------------------------------------------
// GRU (T=256, B=16, HID=1024, EMB=512, VOCAB=32000) + vocab projection.
//   prep_*  : cast weights/embeddings to bf16 (proven R1+)
//   gemm_bt : Gx = xe @ Wx^T, separate pre-kernel (R3/R9-proven; in-mega Gx
//             corrupts — R6-R8 bisect)
//   mega    : persistent 256-block kernel (~110KB LDS -> 1 block/CU).
//     blocks 0..63  : GRU recurrence, 16 cols/block (R3-proven math).
//       Sync = PER-WAVE producer flags at 128B stride (R4 retried with the
//       line-contention failure fixed): producer wave stores its rows
//       (uncached -> MALL), drains ITS OWN stores (wave vmcnt), posts its
//       flag; consumer wave's 64 lanes poll exactly the 64 producer-wave
//       flags covering its K-quarter. No grid barrier, no skew accumulation.
//       Slot reads stay CACHED first-touch-after-flag (R3-proven chain).
//     blocks 64..255: pool: 500 Wd-convert items (uncached stores, proven),
//       then 8000 projection tiles gated on the 256 wave flags + conv_done.
//       GRU blocks join the pool after the recurrence.
// ---------------------------------------------------------------------------

using bf16x8 = __attribute__((ext_vector_type(8))) __bf16;
using f32x4  = __attribute__((ext_vector_type(4))) float;

#define GRUB  64
#define TOTB  256
#define NCONV 500                   // Wd convert items (65536 floats each)
#define NTILE 250                   // 32000/128 col tiles
#define NGRP  32                    // 4096/128 row groups (8 timesteps each)
#define NITEM (NCONV + NGRP * NTILE)

__device__ __forceinline__ unsigned short f2bf(float f) {
  unsigned u = __builtin_bit_cast(unsigned, f);
  u += 0x7FFFu + ((u >> 16) & 1u);          // RNE
  return (unsigned short)(u >> 16);
}
__device__ __forceinline__ f32x4 mfma16(bf16x8 a, bf16x8 b, f32x4 c) {
  return __builtin_amdgcn_mfma_f32_16x16x32_bf16(a, b, c, 0, 0, 0);
}
__device__ __forceinline__ bf16x8 bc8(uint4 v) { return __builtin_bit_cast(bf16x8, v); }

__device__ __forceinline__ void ust32(unsigned* p, unsigned v) {
  __hip_atomic_store(p, v, __ATOMIC_RELAXED, __HIP_MEMORY_SCOPE_AGENT);
}
__device__ __forceinline__ void ust64(unsigned long long* p, unsigned long long v) {
  __hip_atomic_store(p, v, __ATOMIC_RELAXED, __HIP_MEMORY_SCOPE_AGENT);
}
__device__ __forceinline__ unsigned uld32(const unsigned* p) {
  return __hip_atomic_load(p, __ATOMIC_RELAXED, __HIP_MEMORY_SCOPE_AGENT);
}

// ---------------- prep kernels ----------------

__global__ void prep_w(const float* __restrict__ Wz, const float* __restrict__ Wr,
                       const float* __restrict__ Wm,
                       unsigned short* __restrict__ Whall,
                       unsigned short* __restrict__ Wxall) {
  int i = blockIdx.x * 256 + threadIdx.x;
  int g   = i / 393216;            // 1024*1536/4
  int rem = i % 393216;
  int j   = rem / 384;             // 1536/4
  int k   = (rem % 384) * 4;
  const float* src = (g == 0) ? Wz : (g == 1) ? Wr : Wm;
  float4 v = *(const float4*)(src + (size_t)j * 1536 + k);
  ushort4 o;
  o.x = f2bf(v.x); o.y = f2bf(v.y); o.z = f2bf(v.z); o.w = f2bf(v.w);
  if (k < 1024)
    *(ushort4*)(Whall + ((size_t)(g * 1024 + j) * 1024 + k)) = o;
  else
    *(ushort4*)(Wxall + ((size_t)(g * 1024 + j) * 512 + (k - 1024))) = o;
}

__global__ void prep_xe(const int* __restrict__ x, const float* __restrict__ emb,
                        unsigned short* __restrict__ xebf) {
  int i  = blockIdx.x * 256 + threadIdx.x;
  int tb = i >> 7, k = (i & 127) * 4;
  int tok = x[tb];
  float4 v = *(const float4*)(emb + (size_t)tok * 512 + k);
  ushort4 o;
  o.x = f2bf(v.x); o.y = f2bf(v.y); o.z = f2bf(v.z); o.w = f2bf(v.w);
  *(ushort4*)(xebf + (size_t)tb * 512 + k) = o;
}

__global__ void prep_h(const float* __restrict__ h, unsigned short* __restrict__ hbf) {
  int i = blockIdx.x * 256 + threadIdx.x;
  hbf[i] = f2bf(h[i]);
}

// ---------------- GEMM: C[M,N] = A[M,K] x B[N,K]^T (Gx precompute) ---------
__global__ __launch_bounds__(256) void gemm_bt(
    const unsigned short* __restrict__ A, const unsigned short* __restrict__ B,
    float* __restrict__ C, int M, int N, int K, int lda, int ldb, int ldc) {
  __shared__ uint4 As[128 * 5];
  __shared__ uint4 Bs[128 * 5];
  const int tid  = threadIdx.x;
  const int wid  = tid >> 6, lane = tid & 63;
  const int wr   = wid >> 1, wc = wid & 1;
  const int m0   = blockIdx.x * 128, n0 = blockIdx.y * 128;
  const int lr   = lane & 15, lk = lane >> 4;

  f32x4 acc[4][4] = {};
  const int nk = K >> 5;
  for (int kt = 0; kt < nk; ++kt) {
#pragma unroll
    for (int c = 0; c < 2; ++c) {
      int chunk = c * 256 + tid;
      int row = chunk >> 2, kc = chunk & 3;
      As[row * 5 + kc] = *(const uint4*)(A + (size_t)(m0 + row) * lda + kt * 32 + kc * 8);
      Bs[row * 5 + kc] = *(const uint4*)(B + (size_t)(n0 + row) * ldb + kt * 32 + kc * 8);
    }
    __syncthreads();
    bf16x8 af[4], bg[4];
#pragma unroll
    for (int i = 0; i < 4; ++i) {
      af[i] = bc8(As[(wr * 64 + i * 16 + lr) * 5 + lk]);
      bg[i] = bc8(Bs[(wc * 64 + i * 16 + lr) * 5 + lk]);
    }
#pragma unroll
    for (int i = 0; i < 4; ++i)
#pragma unroll
      for (int j = 0; j < 4; ++j)
        acc[i][j] = mfma16(af[i], bg[j], acc[i][j]);
    __syncthreads();
  }
#pragma unroll
  for (int i = 0; i < 4; ++i) {
    int mb = m0 + wr * 64 + i * 16 + lk * 4;
#pragma unroll
    for (int j = 0; j < 4; ++j) {
      int n = n0 + wc * 64 + j * 16 + lr;
#pragma unroll
      for (int q = 0; q < 4; ++q)
        C[(size_t)(mb + q) * ldc + n] = acc[i][j][q];
    }
  }
}

// ---------------- mega kernel ----------------
// flags (uints): [(bid*4+wq)*32] per-WAVE phase seq (256 wave-flags,
// 128B stride); [8192] pool ticket; [8224] conv_done.

__global__ __launch_bounds__(256, 1) void mega(
    const unsigned short* __restrict__ Whall, const float* __restrict__ Gx,
    const unsigned short* __restrict__ h0bf, const float* __restrict__ h0f,
    unsigned short* __restrict__ rhs, float* __restrict__ outh,
    unsigned short* __restrict__ allh,
    const float* __restrict__ Wd, unsigned short* __restrict__ Wdbf,
    float* __restrict__ outy, unsigned* __restrict__ flags) {
  __shared__ uint4 smem[6920];                 // 110,720 B -> 1 block/CU
  const int tid = threadIdx.x;
  const int bid = blockIdx.x;
  unsigned* ctrp  = flags + 8192;
  unsigned* convp = flags + 8224;

  if (bid < GRUB) {
    // ------------- GRU recurrence (16 cols/block; R3-proven math) -------
    uint4* Wl = smem;                                          // 6144 uint4
    float (*red)[4][16][16] = (float (*)[4][16][16])(smem + 6144); // 3 slots
    const int lane = tid & 63, wq = tid >> 6;
    const int c0   = bid * 16;
    const int lr   = lane & 15, lk = lane >> 4;
    const int bKu  = wq * 32;

    for (int it = 0; it < 24; ++it) {
      int chunk = it * 256 + tid;              // 0..6143
      int g = chunk >> 11, rem = chunk & 2047;
      int cl = rem >> 7, k8 = rem & 127;
      uint4 v = *(const uint4*)(Whall + ((size_t)(g * 1024 + c0 + cl) * 1024 + k8 * 8));
      Wl[(g * 16 + cl) * 128 + (k8 ^ (cl & 7))] = v;
    }

    const int b_  = tid >> 4, cl_ = tid & 15;
    const int cg  = c0 + cl_;
    // my wave's flag; the 64 producer-wave flags my wave's K-quarter needs
    unsigned* myflag = flags + (size_t)((bid << 2) + wq) * 32;
    const unsigned* pollf =
        flags + (size_t)(((16 * wq + (lane >> 2)) << 2) + (lane & 3)) * 32;
    float hp = h0f[b_ * 1024 + cg];            // h lives in registers
    float zv = 0.f;
    __syncthreads();

    for (int t = 0; t < 256; ++t) {
      const size_t tb = (size_t)t * 16 + b_;
      // Gx prefetch (cached; completes under the poll)
      float gz = Gx[tb * 3072 + cg];
      float gr = Gx[tb * 3072 + 1024 + cg];
      float gc = Gx[tb * 3072 + 2048 + cg];

      // ---- wait for h_{t-1} rows of my K-quarter (64 wave-flags) ----
      if (t > 0) {
        unsigned seq = 2u * (unsigned)t;
        while (uld32(pollf) < seq) {}
      }
      asm volatile("" ::: "memory");

      // ---- phase 1: z, r (h_prev read CACHED from write-once slot) ----
      const uint4* hp4 = (t == 0) ? (const uint4*)h0bf
                                  : (const uint4*)(allh + (size_t)(t - 1) * 16384);
      f32x4 az = {}, ar = {};
#pragma unroll
      for (int kk = 0; kk < 8; ++kk) {
        int ku = bKu + kk * 4 + lk;            // 0..127
        bf16x8 a  = bc8(hp4[lr * 128 + ku]);
        bf16x8 bz = bc8(Wl[(0 * 16 + lr) * 128 + (ku ^ (lr & 7))]);
        bf16x8 br = bc8(Wl[(1 * 16 + lr) * 128 + (ku ^ (lr & 7))]);
        az = mfma16(a, bz, az);
        ar = mfma16(a, br, ar);
      }
#pragma unroll
      for (int q = 0; q < 4; ++q) {
        red[0][wq][lk * 4 + q][lr] = az[q];
        red[1][wq][lk * 4 + q][lr] = ar[q];
      }
      __syncthreads();
      {
        float sz = red[0][0][b_][cl_] + red[0][1][b_][cl_] + red[0][2][b_][cl_] +
                   red[0][3][b_][cl_] + gz;
        float sr = red[1][0][b_][cl_] + red[1][1][b_][cl_] + red[1][2][b_][cl_] +
                   red[1][3][b_][cl_] + gr;
        zv = 1.f / (1.f + __expf(-sz));
        float rv = 1.f / (1.f + __expf(-sr));
        unsigned short my = f2bf(rv * hp);
        unsigned other = __shfl_xor((unsigned)my, 1);
        if ((cl_ & 1) == 0)
          ust32((unsigned*)rhs + (((size_t)t * 16384 + b_ * 1024 + cg) >> 1),
                (unsigned)my | (other << 16));
      }
      // wave-level drain of MY stores, then post MY wave flag
      asm volatile("s_waitcnt vmcnt(0)" ::: "memory");
      if (lane == 0) ust32(myflag, 2u * (unsigned)t + 1u);

      // ---- wait for rh rows of my K-quarter ----
      {
        unsigned seq = 2u * (unsigned)t + 1u;
        while (uld32(pollf) < seq) {}
      }
      asm volatile("" ::: "memory");

      // ---- phase 2: cand, h_new (rh read CACHED from write-once slot) ----
      const uint4* rt4 = (const uint4*)(rhs + (size_t)t * 16384);
      f32x4 ac = {};
#pragma unroll
      for (int kk = 0; kk < 8; ++kk) {
        int ku = bKu + kk * 4 + lk;
        bf16x8 a  = bc8(rt4[lr * 128 + ku]);
        bf16x8 bc = bc8(Wl[(2 * 16 + lr) * 128 + (ku ^ (lr & 7))]);
        ac = mfma16(a, bc, ac);
      }
#pragma unroll
      for (int q = 0; q < 4; ++q) red[2][wq][lk * 4 + q][lr] = ac[q];
      __syncthreads();
      float hn;
      {
        float sc = red[2][0][b_][cl_] + red[2][1][b_][cl_] + red[2][2][b_][cl_] +
                   red[2][3][b_][cl_] + gc;
        float cand = tanhf(sc);
        hn = (1.f - zv) * hp + zv * cand;
        hp = hn;
        unsigned short my = f2bf(hn);
        unsigned other = __shfl_xor((unsigned)my, 1);
        if ((cl_ & 1) == 0)
          ust32((unsigned*)allh + (((size_t)t * 16384 + b_ * 1024 + cg) >> 1),
                (unsigned)my | (other << 16));
      }
      asm volatile("s_waitcnt vmcnt(0)" ::: "memory");
      if (lane == 0) ust32(myflag, 2u * (unsigned)t + 2u);
      outh[tb * 1024 + cg] = hn;               // cached, off the critical path
    }
  }

  // ------------- work pool: Wd convert, then projection -------------
  __syncthreads();
  uint4* As = smem;
  uint4* Bs = smem + 640;
  unsigned* wsh = (unsigned*)(smem + 6912);
  const int wid = tid >> 6, lane = tid & 63;
  const int wr = wid >> 1, wc = wid & 1;
  const int lr = lane & 15, lk = lane >> 4;

  for (;;) {
    __syncthreads();
    if (tid == 0)
      *wsh = __hip_atomic_fetch_add(ctrp, 1u, __ATOMIC_RELAXED,
                                    __HIP_MEMORY_SCOPE_AGENT);
    __syncthreads();
    unsigned w = *wsh;
    if (w >= (unsigned)NITEM) break;

    if (w < (unsigned)NCONV) {
      // convert 65536 floats of Wd -> Wdbf, UNCACHED 8B stores (proven)
      const float4* src = (const float4*)Wd + (size_t)w * 16384;
      unsigned long long* dst = (unsigned long long*)Wdbf + (size_t)w * 16384;
      for (int it = 0; it < 64; ++it) {
        int idx = it * 256 + tid;
        float4 v = src[idx];
        ushort4 o;
        o.x = f2bf(v.x); o.y = f2bf(v.y); o.z = f2bf(v.z); o.w = f2bf(v.w);
        ust64(dst + idx, __builtin_bit_cast(unsigned long long, o));
      }
      asm volatile("s_waitcnt vmcnt(0)" ::: "memory");
      __syncthreads();
      if (tid == 0)
        __hip_atomic_fetch_add(convp, 1u, __ATOMIC_RELAXED, __HIP_MEMORY_SCOPE_AGENT);
      continue;
    }

    unsigned p = w - NCONV;
    int g = (int)(p / NTILE), nt = (int)(p % NTILE);
    int m0 = g * 128, n0 = nt * 128;

    // gate: all 256 GRU wave-flags past phase seq 16g+16 (steps <= 8g+7
    // drained to MALL) + converts finished
    unsigned tgt = 16u * (unsigned)g + 16u;
    {
      const unsigned* f = flags + (size_t)tid * 32;   // tid<256 covers all
      while (uld32(f) < tgt) __builtin_amdgcn_s_sleep(8);
    }
    if (tid == 0)
      while (uld32(convp) < (unsigned)NCONV) __builtin_amdgcn_s_sleep(8);
    __syncthreads();

    f32x4 acc[4][4] = {};
    for (int kt = 0; kt < 32; ++kt) {
#pragma unroll
      for (int c = 0; c < 2; ++c) {
        int chunk = c * 256 + tid;
        int row = chunk >> 2, kc = chunk & 3;
        As[row * 5 + kc] = *(const uint4*)(allh + (size_t)(m0 + row) * 1024 + kt * 32 + kc * 8);
        Bs[row * 5 + kc] = *(const uint4*)(Wdbf + (size_t)(n0 + row) * 1024 + kt * 32 + kc * 8);
      }
      __syncthreads();
      bf16x8 afr[4], bg[4];
#pragma unroll
      for (int i = 0; i < 4; ++i) {
        afr[i] = bc8(As[(wr * 64 + i * 16 + lr) * 5 + lk]);
        bg[i]  = bc8(Bs[(wc * 64 + i * 16 + lr) * 5 + lk]);
      }
#pragma unroll
      for (int i = 0; i < 4; ++i)
#pragma unroll
        for (int j = 0; j < 4; ++j)
          acc[i][j] = mfma16(afr[i], bg[j], acc[i][j]);
      __syncthreads();
    }
#pragma unroll
    for (int i = 0; i < 4; ++i) {
      int mb = m0 + wr * 64 + i * 16 + lk * 4;
#pragma unroll
      for (int j = 0; j < 4; ++j) {
        int n = n0 + wc * 64 + j * 16 + lr;
#pragma unroll
        for (int q = 0; q < 4; ++q)
          outy[(size_t)(mb + q) * 32000 + n] = acc[i][j][q];
      }
    }
  }
}

// ---------------- workspace layout (bytes) ----------------
constexpr size_t OFF_WH  = 0;                                  // 6.3 MB
constexpr size_t OFF_WX  = OFF_WH + 3ull * 1024 * 1024 * 2;    // 3.1 MB
constexpr size_t OFF_WD  = OFF_WX + 3ull * 1024 * 512 * 2;     // 65.5 MB
constexpr size_t OFF_XE  = OFF_WD + 32000ull * 1024 * 2;       // 4.2 MB
constexpr size_t OFF_GX  = OFF_XE + 4096ull * 512 * 2;         // 50.3 MB
constexpr size_t OFF_AH  = OFF_GX + 4096ull * 3072 * 4;        // 8.4 MB
constexpr size_t OFF_H0  = OFF_AH + 4096ull * 1024 * 2;        // 32 KB
constexpr size_t OFF_RHS = OFF_H0 + 16384ull * 2;              // 8.4 MB
constexpr size_t OFF_FLG = OFF_RHS + 256ull * 16384 * 2;       // 36 KB flags

extern "C" void kernel_launch(void* const* d_in, const int* in_sizes, int n_in,
                              void* d_out, int out_size, void* d_ws, size_t ws_size,
                              hipStream_t stream) {
  const int*   x   = (const int*)d_in[0];
  const float* h0  = (const float*)d_in[1];
  const float* emb = (const float*)d_in[2];
  const float* Wz  = (const float*)d_in[3];
  const float* Wr  = (const float*)d_in[4];
  const float* Wm  = (const float*)d_in[5];
  const float* Wd  = (const float*)d_in[6];

  float* out_h = (float*)d_out;                        // [256*16, 1024]
  float* out_y = out_h + 4096ull * 1024;               // [256*16, 32000]

  char* ws = (char*)d_ws;
  unsigned short* Whall = (unsigned short*)(ws + OFF_WH);
  unsigned short* Wxall = (unsigned short*)(ws + OFF_WX);
  unsigned short* Wdbf  = (unsigned short*)(ws + OFF_WD);
  unsigned short* xebf  = (unsigned short*)(ws + OFF_XE);
  float*          Gx    = (float*)(ws + OFF_GX);
  unsigned short* allh  = (unsigned short*)(ws + OFF_AH);
  unsigned short* h0bf  = (unsigned short*)(ws + OFF_H0);
  unsigned short* rhs   = (unsigned short*)(ws + OFF_RHS);
  unsigned*       flags = (unsigned*)(ws + OFF_FLG);

  hipMemsetAsync(flags, 0, 36864, stream);

  prep_w <<<4608, 256, 0, stream>>>(Wz, Wr, Wm, Whall, Wxall);
  prep_xe<<<2048, 256, 0, stream>>>(x, emb, xebf);
  prep_h <<<64, 256, 0, stream>>>(h0, h0bf);

  // Gx[tb][g*1024+c] = xe[tb] . Wx_g[c]   (M=4096, N=3072, K=512)
  gemm_bt<<<dim3(32, 24), 256, 0, stream>>>(xebf, Wxall, Gx,
                                            4096, 3072, 512, 512, 512, 3072);

  mega<<<TOTB, 256, 0, stream>>>(Whall, Gx, h0bf, h0, rhs,
                                 out_h, allh, Wd, Wdbf, out_y, flags);
}